// Round 20
// baseline (389.052 us; speedup 1.0000x reference)
//
#include <hip/hip_runtime.h>
#include <hip/hip_bf16.h>

// Sizes fixed by the reference
#define HV   128
#define HT   17
#define DIMD 290        // 2*(HV+HT)
#define KP   320        // K padded to 10*32 for mfma 16x16x32
#define OO   640        // 5*HV
#define RT   32         // rows per tile (32 -> 2 blocks/CU at <=128 regs)
#define KN   8          // number of types
#define NXCD 8

typedef unsigned short u16;
typedef __attribute__((ext_vector_type(8))) short short8v;
typedef __attribute__((ext_vector_type(4))) float f32x4;

__device__ __forceinline__ u16 f2bf(float x) {
    __hip_bfloat16 b = __float2bfloat16(x);
    return __builtin_bit_cast(u16, b);
}
__device__ __forceinline__ ushort4 f2bf4(float4 v) {
    ushort4 r;
    r.x = f2bf(v.x); r.y = f2bf(v.y); r.z = f2bf(v.z); r.w = f2bf(v.w);
    return r;
}
__device__ __forceinline__ float sigf(float x) {
    return __builtin_amdgcn_rcpf(1.0f + __expf(-x));
}
__device__ __forceinline__ float tanhfast(float x) {
    return 1.0f - 2.0f * __builtin_amdgcn_rcpf(1.0f + __expf(2.0f * x));
}

// ws header layout (ints): [0..7] counts, [8..15] scatter cursors,
// [16..24] blkStart prefix (blkStart[8] = total row-tiles)

__global__ void hist_k(const int* __restrict__ pt, int* __restrict__ hdr, int N) {
    __shared__ int c[KN];
    if (threadIdx.x < KN) c[threadIdx.x] = 0;
    __syncthreads();
    int n = blockIdx.x * 256 + threadIdx.x;
    if (n < N) atomicAdd(&c[pt[n]], 1);
    __syncthreads();
    if (threadIdx.x < KN && c[threadIdx.x]) atomicAdd(&hdr[threadIdx.x], c[threadIdx.x]);
}

__global__ void prefix_k(int* __restrict__ hdr) {
    if (threadIdx.x == 0 && blockIdx.x == 0) {
        int acc = 0;
        hdr[16] = 0;
        for (int k = 0; k < KN; ++k) {
            acc += (hdr[k] + RT - 1) / RT;
            hdr[17 + k] = acc;
        }
    }
}

__global__ void scatter_k(const int* __restrict__ pt, int* __restrict__ hdr,
                          int* __restrict__ idxbuf, int N) {
    __shared__ int c[KN], base[KN];
    if (threadIdx.x < KN) c[threadIdx.x] = 0;
    __syncthreads();
    int n = blockIdx.x * 256 + threadIdx.x;
    int k = 0, my = 0;
    if (n < N) { k = pt[n]; my = atomicAdd(&c[k], 1); }
    __syncthreads();
    if (threadIdx.x < KN)
        base[threadIdx.x] = c[threadIdx.x] ? atomicAdd(&hdr[8 + threadIdx.x], c[threadIdx.x]) : 0;
    __syncthreads();
    if (n < N) idxbuf[hdr[16 + k] * RT + base[k] + my] = n;
}

// W (K,O,290) fp32 -> Wt (K, 10, 640, 32) bf16, K-major-tiled + column perm.
// x' layout = [h_l 0..128 | h_r 128..256 | t_l 256..273 | t_r 273..290 | 0 pad]
__global__ void wconv_k(const float* __restrict__ W, u16* __restrict__ Wt) {
    int k = blockIdx.y;
    int idx = blockIdx.x * 256 + threadIdx.x;
    if (idx >= OO * KP) return;
    int o = idx / KP, d = idx % KP;
    int src;
    if (d < 256)      src = (d < 128) ? d : d + 17;
    else if (d < 273) src = d - 128;
    else if (d < 290) src = d;
    else              src = -1;
    float v = (src >= 0) ? W[((size_t)k * OO + o) * DIMD + src] : 0.0f;
    int kk = d >> 5, e = d & 31;
    Wt[(((size_t)k * 10 + kk) * OO + o) * 32 + e] = f2bf(v);
}

// Fused gather + GEMM + LSTM, 2 tiles/block, 32-row tiles, CLEAN-FIFO schedule.
// 8 waves, wave = 32 rows x 16 hcols x 5 gates -> acc[5][2] = 40 AGPR;
// __launch_bounds__(512,4) caps total regs at 128 -> 4 waves/SIMD = 2
// independent blocks/CU whose phases overlap (gather of one hides under the
// MFMA loop of the other). W-loads are the ONLY vm ops inside the loop.
__global__ __launch_bounds__(512, 4)
void fused_k(const float* __restrict__ h_pool, const float* __restrict__ c_pool,
             const float* __restrict__ t_pool, const int* __restrict__ child_idx,
             const float* __restrict__ bias, const u16* __restrict__ Wt,
             const int* __restrict__ hdr, const int* __restrict__ idxbuf,
             float* __restrict__ out) {
    __shared__ u16 sX[RT * KP];          // 20480 B, XOR-swizzled rows
    __shared__ int4 sMeta[2][RT];

    const int ntiles = hdr[24];

    // bijective XCD-chunk swizzle (m204)
    const int nwg = gridDim.x;
    const int bq = nwg >> 3, br = nwg & (NXCD - 1);
    const int xcd = blockIdx.x & (NXCD - 1), ixc = blockIdx.x >> 3;
    const int sbid = (xcd < br ? xcd * (bq + 1) : br * (bq + 1) + (xcd - br) * bq) + ixc;

    const int t0 = sbid * 2;
    if (t0 >= ntiles) return;
    const int t1 = t0 + 1;
    const bool has1 = (t1 < ntiles);

    const int tid = threadIdx.x;
    const int r = tid >> 4, q = tid & 15;    // 16 threads per row

    float4 A0[2], B0[2];
    float Tl0, Tl2 = 0.f, Tr0, Tr2 = 0.f;
    int sn, sl, sr2;

    auto loadmeta = [&](int tile) {
        sn = idxbuf[tile * RT + r];
        sl = 0; sr2 = 0;
        if (sn >= 0) { sl = child_idx[2 * sn]; sr2 = child_idx[2 * sn + 1]; }
    };
    auto issue_stage = [&]() {
        if (sn < 0) return;
        const float4* hl = (const float4*)(h_pool + (size_t)sl * HV);
        const float4* hr = (const float4*)(h_pool + (size_t)sr2 * HV);
        #pragma unroll
        for (int m = 0; m < 2; ++m) A0[m] = hl[q + 16 * m];
        #pragma unroll
        for (int m = 0; m < 2; ++m) B0[m] = hr[q + 16 * m];
        const float* tl = t_pool + (size_t)sl * HT;
        const float* tr = t_pool + (size_t)sr2 * HT;
        Tl0 = tl[q]; Tr0 = tr[q];
        if (q == 0) { Tl2 = tl[16]; Tr2 = tr[16]; }
    };
    auto write_stage = [&]() {
        char* xr = (char*)sX + r * 640;
        const int swz = (r & 7) << 4;
        if (sn >= 0) {
            #pragma unroll
            for (int m = 0; m < 2; ++m)
                *(ushort4*)(xr + (((q + 16 * m) * 8) ^ swz)) = f2bf4(A0[m]);
            #pragma unroll
            for (int m = 0; m < 2; ++m)
                *(ushort4*)(xr + ((256 + (q + 16 * m) * 8) ^ swz)) = f2bf4(B0[m]);
            *(u16*)(xr + ((512 + 2 * q) ^ swz)) = f2bf(Tl0);
            *(u16*)(xr + ((546 + 2 * q) ^ swz)) = f2bf(Tr0);
            if (q == 0) {
                *(u16*)(xr + (544 ^ swz)) = f2bf(Tl2);
                *(u16*)(xr + (578 ^ swz)) = f2bf(Tr2);
            }
            for (int b = 580 + 2 * q; b < 640; b += 32)
                *(u16*)(xr + (b ^ swz)) = 0;
        } else {
            ushort4 z = make_ushort4(0, 0, 0, 0);
            for (int b = q * 8; b < 640; b += 128)
                *(ushort4*)(xr + (b ^ swz)) = z;
        }
    };

    // ---- phase 1: stage tile t0 into LDS ----
    loadmeta(t0);
    if (q == 0) sMeta[0][r] = make_int4(sn, sl, sr2, 0);
    issue_stage();
    write_stage();
    __syncthreads();   // full drain: vm FIFO EMPTY entering the loop

    const int wc = tid >> 6, lane = tid & 63;
    const int lo = lane & 15, hi = lane >> 4;
    const int hcol = wc * 16 + lo;
    const char* sXb = (const char*)sX;
    const int rowbase = lo * 640;
    const int swzl = (lo & 7) << 4;

    int k0 = 0;
    #pragma unroll
    for (int j = 0; j < 7; ++j) k0 += (t0 >= hdr[17 + j]);

    int wo[5];
    #pragma unroll
    for (int g = 0; g < 5; ++g)
        wo[g] = (g * 128 + hcol) * 32 + hi * 8;

    // ---- tile t0: CLEAN MFMA loop (1-deep W lookahead, only W in vm FIFO) ----
    f32x4 acc[5][2];
    #pragma unroll
    for (int g = 0; g < 5; ++g)
        #pragma unroll
        for (int m = 0; m < 2; ++m)
            acc[g][m] = (f32x4){0.f, 0.f, 0.f, 0.f};

    {
        const u16* __restrict__ wt = Wt + ((size_t)k0 * 10 * OO) * 32;
        short8v wfa[5], wfb[5];
        #pragma unroll
        for (int g = 0; g < 5; ++g) wfa[g] = *(const short8v*)(wt + wo[g]);

        #pragma unroll
        for (int kk = 0; kk < 10; ++kk) {
            short8v (&wcur)[5] = (kk & 1) ? wfb : wfa;
            short8v (&wnxt)[5] = (kk & 1) ? wfa : wfb;
            if (kk < 9) {
                const u16* wtn = wt + (size_t)(kk + 1) * (OO * 32);
                #pragma unroll
                for (int g = 0; g < 5; ++g)
                    wnxt[g] = *(const short8v*)(wtn + wo[g]);
            }
            int a_off = rowbase + ((kk * 64 + hi * 16) ^ swzl);
            short8v a0 = *(const short8v*)(sXb + a_off);
            short8v a1 = *(const short8v*)(sXb + a_off + 10240);
            #pragma unroll
            for (int g = 0; g < 5; ++g) {
                acc[g][0] = __builtin_amdgcn_mfma_f32_16x16x32_bf16(a0, wcur[g], acc[g][0], 0, 0, 0);
                acc[g][1] = __builtin_amdgcn_mfma_f32_16x16x32_bf16(a1, wcur[g], acc[g][1], 0, 0, 0);
            }
        }
    }

    // ---- phase 3: issue t1 gather FIRST (oldest), then bias, then c(t0) ----
    if (has1) {
        loadmeta(t1);
        if (q == 0) sMeta[1][r] = make_int4(sn, sl, sr2, 0);
        issue_stage();
    }
    __builtin_amdgcn_sched_barrier(0);   // pin: gather issued before c-loads

    float bb[5];
    #pragma unroll
    for (int g = 0; g < 5; ++g) bb[g] = bias[k0 * OO + g * 128 + hcol];

    int nodes[8];
    float cpl[8], cpr[8];
    #pragma unroll
    for (int m = 0; m < 2; ++m)
        #pragma unroll
        for (int jj = 0; jj < 4; ++jj) {
            int4 mt = sMeta[0][m * 16 + hi * 4 + jj];
            nodes[m * 4 + jj] = mt.x;
            cpl[m * 4 + jj] = c_pool[(size_t)mt.y * HV + hcol];
            cpr[m * 4 + jj] = c_pool[(size_t)mt.z * HV + hcol];
        }

    // ---- phase 4: epilogue t0 (c-wait drains the t1 gather for free) ----
    #pragma unroll
    for (int m = 0; m < 2; ++m) {
        #pragma unroll
        for (int jj = 0; jj < 4; ++jj) {
            int node = nodes[m * 4 + jj];
            if (node < 0) continue;
            float cl = cpl[m * 4 + jj], cr = cpr[m * 4 + jj];
            float gi  = acc[0][m][jj] + bb[0];
            float gfl = acc[1][m][jj] + bb[1];
            float gfr = acc[2][m][jj] + bb[2];
            float gu  = acc[3][m][jj] + bb[3];
            float go  = acc[4][m][jj] + bb[4];
            float cc = sigf(gi) * tanhfast(gu) + sigf(gfl) * cl + sigf(gfr) * cr;
            float hh = sigf(go) * tanhfast(cc);
            float* orow = out + (size_t)node * (2 * HV);
            orow[hcol]      = hh;
            orow[HV + hcol] = cc;
        }
    }

    if (!has1) return;

    // ---- phase 5: swap LDS to tile t1 (lgkm-only barriers) ----
    __builtin_amdgcn_s_barrier();                         // all waves done reading sX[t0]
    write_stage();
    asm volatile("s_waitcnt lgkmcnt(0)" ::: "memory");    // t1 LDS visible
    __builtin_amdgcn_s_barrier();

    // ---- tile t1: clean MFMA loop ----
    int k1 = 0;
    #pragma unroll
    for (int j = 0; j < 7; ++j) k1 += (t1 >= hdr[17 + j]);

    #pragma unroll
    for (int g = 0; g < 5; ++g)
        #pragma unroll
        for (int m = 0; m < 2; ++m)
            acc[g][m] = (f32x4){0.f, 0.f, 0.f, 0.f};

    {
        const u16* __restrict__ wt = Wt + ((size_t)k1 * 10 * OO) * 32;
        short8v wfa[5], wfb[5];
        #pragma unroll
        for (int g = 0; g < 5; ++g) wfa[g] = *(const short8v*)(wt + wo[g]);

        #pragma unroll
        for (int kk = 0; kk < 10; ++kk) {
            short8v (&wcur)[5] = (kk & 1) ? wfb : wfa;
            short8v (&wnxt)[5] = (kk & 1) ? wfa : wfb;
            if (kk < 9) {
                const u16* wtn = wt + (size_t)(kk + 1) * (OO * 32);
                #pragma unroll
                for (int g = 0; g < 5; ++g)
                    wnxt[g] = *(const short8v*)(wtn + wo[g]);
            }
            int a_off = rowbase + ((kk * 64 + hi * 16) ^ swzl);
            short8v a0 = *(const short8v*)(sXb + a_off);
            short8v a1 = *(const short8v*)(sXb + a_off + 10240);
            #pragma unroll
            for (int g = 0; g < 5; ++g) {
                acc[g][0] = __builtin_amdgcn_mfma_f32_16x16x32_bf16(a0, wcur[g], acc[g][0], 0, 0, 0);
                acc[g][1] = __builtin_amdgcn_mfma_f32_16x16x32_bf16(a1, wcur[g], acc[g][1], 0, 0, 0);
            }
        }
    }

    // ---- t1 epilogue: bias + c after the loop ----
    #pragma unroll
    for (int g = 0; g < 5; ++g) bb[g] = bias[k1 * OO + g * 128 + hcol];

    #pragma unroll
    for (int m = 0; m < 2; ++m)
        #pragma unroll
        for (int jj = 0; jj < 4; ++jj) {
            int4 mt = sMeta[1][m * 16 + hi * 4 + jj];
            nodes[m * 4 + jj] = mt.x;
            cpl[m * 4 + jj] = c_pool[(size_t)mt.y * HV + hcol];
            cpr[m * 4 + jj] = c_pool[(size_t)mt.z * HV + hcol];
        }

    #pragma unroll
    for (int m = 0; m < 2; ++m) {
        #pragma unroll
        for (int jj = 0; jj < 4; ++jj) {
            int node = nodes[m * 4 + jj];
            if (node < 0) continue;
            float cl = cpl[m * 4 + jj], cr = cpr[m * 4 + jj];
            float gi  = acc[0][m][jj] + bb[0];
            float gfl = acc[1][m][jj] + bb[1];
            float gfr = acc[2][m][jj] + bb[2];
            float gu  = acc[3][m][jj] + bb[3];
            float go  = acc[4][m][jj] + bb[4];
            float cc = sigf(gi) * tanhfast(gu) + sigf(gfl) * cl + sigf(gfr) * cr;
            float hh = sigf(go) * tanhfast(cc);
            float* orow = out + (size_t)node * (2 * HV);
            orow[hcol]      = hh;
            orow[HV + hcol] = cc;
        }
    }
}

extern "C" void kernel_launch(void* const* d_in, const int* in_sizes, int n_in,
                              void* d_out, int out_size, void* d_ws, size_t ws_size,
                              hipStream_t stream) {
    const float* h_pool      = (const float*)d_in[0];
    const float* c_pool      = (const float*)d_in[1];
    const float* t_pool      = (const float*)d_in[2];
    const int*   child_idx   = (const int*)d_in[3];
    const int*   parent_type = (const int*)d_in[4];
    const float* W           = (const float*)d_in[5];
    const float* bias        = (const float*)d_in[6];
    float* out = (float*)d_out;

    const int N = in_sizes[3] / 2;
    const int maxblk = (N + RT - 1) / RT + KN;    // upper bound on row-tiles
    const int totrows = maxblk * RT;

    char* ws = (char*)d_ws;
    size_t off = 0;
    int* hdr = (int*)ws;                         off += 1024;
    int* idxbuf = (int*)(ws + off);              off += (((size_t)totrows * 4 + 255) / 256) * 256;
    u16* Wt = (u16*)(ws + off);                  off += (size_t)KN * OO * KP * 2;

    hipMemsetAsync(hdr, 0, 1024, stream);
    hipMemsetAsync(idxbuf, 0xFF, (size_t)totrows * 4, stream);

    int nb = (N + 255) / 256;
    hist_k<<<nb, 256, 0, stream>>>(parent_type, hdr, N);
    prefix_k<<<1, 64, 0, stream>>>(hdr);
    scatter_k<<<nb, 256, 0, stream>>>(parent_type, hdr, idxbuf, N);
    wconv_k<<<dim3((OO * KP + 255) / 256, KN), 256, 0, stream>>>(W, Wt);
    fused_k<<<(maxblk + 1) / 2, 512, 0, stream>>>(
        h_pool, c_pool, t_pool, child_idx, bias, Wt, hdr, idxbuf, out);
}

// Round 21
// 276.080 us; speedup vs baseline: 1.4092x; 1.4092x over previous
//
#include <hip/hip_runtime.h>
#include <hip/hip_bf16.h>

// Sizes fixed by the reference
#define HV   128
#define HT   17
#define DIMD 290        // 2*(HV+HT)
#define KP   320        // K padded to 10*32 for mfma 16x16x32
#define OO   640        // 5*HV
#define RT   64         // rows per tile
#define KN   8          // number of types
#define NXCD 8

typedef unsigned short u16;
typedef __attribute__((ext_vector_type(8))) short short8v;
typedef __attribute__((ext_vector_type(4))) float f32x4;

__device__ __forceinline__ u16 f2bf(float x) {
    __hip_bfloat16 b = __float2bfloat16(x);
    return __builtin_bit_cast(u16, b);
}
__device__ __forceinline__ ushort4 f2bf4(float4 v) {
    ushort4 r;
    r.x = f2bf(v.x); r.y = f2bf(v.y); r.z = f2bf(v.z); r.w = f2bf(v.w);
    return r;
}
__device__ __forceinline__ float sigf(float x) {
    return __builtin_amdgcn_rcpf(1.0f + __expf(-x));
}
__device__ __forceinline__ float tanhfast(float x) {
    return 1.0f - 2.0f * __builtin_amdgcn_rcpf(1.0f + __expf(2.0f * x));
}

// ws header layout (ints): [0..7] counts, [8..15] scatter cursors,
// [16..24] blkStart prefix (blkStart[8] = total row-tiles)

__global__ void hist_k(const int* __restrict__ pt, int* __restrict__ hdr, int N) {
    __shared__ int c[KN];
    if (threadIdx.x < KN) c[threadIdx.x] = 0;
    __syncthreads();
    int n = blockIdx.x * 256 + threadIdx.x;
    if (n < N) atomicAdd(&c[pt[n]], 1);
    __syncthreads();
    if (threadIdx.x < KN && c[threadIdx.x]) atomicAdd(&hdr[threadIdx.x], c[threadIdx.x]);
}

__global__ void prefix_k(int* __restrict__ hdr) {
    if (threadIdx.x == 0 && blockIdx.x == 0) {
        int acc = 0;
        hdr[16] = 0;
        for (int k = 0; k < KN; ++k) {
            acc += (hdr[k] + RT - 1) / RT;
            hdr[17 + k] = acc;
        }
    }
}

__global__ void scatter_k(const int* __restrict__ pt, int* __restrict__ hdr,
                          int* __restrict__ idxbuf, int N) {
    __shared__ int c[KN], base[KN];
    if (threadIdx.x < KN) c[threadIdx.x] = 0;
    __syncthreads();
    int n = blockIdx.x * 256 + threadIdx.x;
    int k = 0, my = 0;
    if (n < N) { k = pt[n]; my = atomicAdd(&c[k], 1); }
    __syncthreads();
    if (threadIdx.x < KN)
        base[threadIdx.x] = c[threadIdx.x] ? atomicAdd(&hdr[8 + threadIdx.x], c[threadIdx.x]) : 0;
    __syncthreads();
    if (n < N) idxbuf[hdr[16 + k] * RT + base[k] + my] = n;
}

// W (K,O,290) fp32 -> Wt (K, 10, 640, 32) bf16, K-major-tiled + column perm.
// x' layout = [h_l 0..128 | h_r 128..256 | t_l 256..273 | t_r 273..290 | 0 pad]
__global__ void wconv_k(const float* __restrict__ W, u16* __restrict__ Wt) {
    int k = blockIdx.y;
    int idx = blockIdx.x * 256 + threadIdx.x;
    if (idx >= OO * KP) return;
    int o = idx / KP, d = idx % KP;
    int src;
    if (d < 256)      src = (d < 128) ? d : d + 17;
    else if (d < 273) src = d - 128;
    else if (d < 290) src = d;
    else              src = -1;
    float v = (src >= 0) ? W[((size_t)k * OO + o) * DIMD + src] : 0.0f;
    int kk = d >> 5, e = d & 31;
    Wt[(((size_t)k * 10 + kk) * OO + o) * 32 + e] = f2bf(v);
}

// Fused gather + GEMM + LSTM, 2 tiles/block, CLEAN-FIFO schedule +
// XCD-chunked tile mapping + 4-deep W prefetch (5 rotating buffers:
// ~390cy slack vs possible L2-miss ~450-900cy W latency).
__global__ __launch_bounds__(512, 2)
void fused_k(const float* __restrict__ h_pool, const float* __restrict__ c_pool,
             const float* __restrict__ t_pool, const int* __restrict__ child_idx,
             const float* __restrict__ bias, const u16* __restrict__ Wt,
             const int* __restrict__ hdr, const int* __restrict__ idxbuf,
             float* __restrict__ out) {
    __shared__ u16 sX[RT * KP];          // 40960 B, XOR-swizzled rows
    __shared__ int4 sMeta[2][RT];

    const int ntiles = hdr[24];

    // bijective XCD-chunk swizzle (m204)
    const int nwg = gridDim.x;
    const int bq = nwg >> 3, br = nwg & (NXCD - 1);
    const int xcd = blockIdx.x & (NXCD - 1), ixc = blockIdx.x >> 3;
    const int sbid = (xcd < br ? xcd * (bq + 1) : br * (bq + 1) + (xcd - br) * bq) + ixc;

    const int t0 = sbid * 2;
    if (t0 >= ntiles) return;
    const int t1 = t0 + 1;
    const bool has1 = (t1 < ntiles);

    const int tid = threadIdx.x;
    const int r = tid >> 3, q = tid & 7;     // 8 threads per row

    float4 A0[4], B0[4];
    float Tl0, Tl1, Tl2 = 0.f, Tr0, Tr1, Tr2 = 0.f;
    int sn, sl, sr2;

    auto loadmeta = [&](int tile) {
        sn = idxbuf[tile * RT + r];
        sl = 0; sr2 = 0;
        if (sn >= 0) { sl = child_idx[2 * sn]; sr2 = child_idx[2 * sn + 1]; }
    };
    auto issue_stage = [&]() {
        if (sn < 0) return;
        const float4* hl = (const float4*)(h_pool + (size_t)sl * HV);
        const float4* hr = (const float4*)(h_pool + (size_t)sr2 * HV);
        #pragma unroll
        for (int m = 0; m < 4; ++m) A0[m] = hl[q + 8 * m];
        #pragma unroll
        for (int m = 0; m < 4; ++m) B0[m] = hr[q + 8 * m];
        const float* tl = t_pool + (size_t)sl * HT;
        const float* tr = t_pool + (size_t)sr2 * HT;
        Tl0 = tl[q]; Tl1 = tl[q + 8];
        Tr0 = tr[q]; Tr1 = tr[q + 8];
        if (q == 0) { Tl2 = tl[16]; Tr2 = tr[16]; }
    };
    auto write_stage = [&]() {
        char* xr = (char*)sX + r * 640;
        const int swz = (r & 7) << 4;
        if (sn >= 0) {
            #pragma unroll
            for (int m = 0; m < 4; ++m)
                *(ushort4*)(xr + (((q + 8 * m) * 8) ^ swz)) = f2bf4(A0[m]);
            #pragma unroll
            for (int m = 0; m < 4; ++m)
                *(ushort4*)(xr + ((256 + (q + 8 * m) * 8) ^ swz)) = f2bf4(B0[m]);
            *(u16*)(xr + ((512 + 2 * q) ^ swz))       = f2bf(Tl0);
            *(u16*)(xr + ((512 + 2 * (q + 8)) ^ swz)) = f2bf(Tl1);
            *(u16*)(xr + ((546 + 2 * q) ^ swz))       = f2bf(Tr0);
            *(u16*)(xr + ((546 + 2 * (q + 8)) ^ swz)) = f2bf(Tr1);
            if (q == 0) {
                *(u16*)(xr + (544 ^ swz)) = f2bf(Tl2);
                *(u16*)(xr + (578 ^ swz)) = f2bf(Tr2);
            }
            for (int b = 580 + 2 * q; b < 640; b += 16)
                *(u16*)(xr + (b ^ swz)) = 0;
        } else {
            ushort4 z = make_ushort4(0, 0, 0, 0);
            for (int b = q * 8; b < 640; b += 64)
                *(ushort4*)(xr + (b ^ swz)) = z;
        }
    };

    // ---- phase 1: stage tile t0 into LDS ----
    loadmeta(t0);
    if (q == 0) sMeta[0][r] = make_int4(sn, sl, sr2, 0);
    issue_stage();
    write_stage();
    __syncthreads();   // full drain: vm FIFO EMPTY entering the loop

    const int wc = tid >> 6, lane = tid & 63;
    const int lo = lane & 15, hi = lane >> 4;
    const int hcol = wc * 16 + lo;
    const char* sXb = (const char*)sX;
    const int rowbase = lo * 640;
    const int swzl = (lo & 7) << 4;

    int k0 = 0;
    #pragma unroll
    for (int j = 0; j < 7; ++j) k0 += (t0 >= hdr[17 + j]);

    int wo[5];
    #pragma unroll
    for (int g = 0; g < 5; ++g)
        wo[g] = (g * 128 + hcol) * 32 + hi * 8;

    // ---- tile t0: CLEAN MFMA loop, 4-deep W prefetch (5 buffers) ----
    f32x4 acc[5][4];
    #pragma unroll
    for (int g = 0; g < 5; ++g)
        #pragma unroll
        for (int m = 0; m < 4; ++m)
            acc[g][m] = (f32x4){0.f, 0.f, 0.f, 0.f};

    {
        const u16* __restrict__ wt = Wt + ((size_t)k0 * 10 * OO) * 32;
        short8v w0[5], w1[5], w2[5], w3[5], w4[5];
        #pragma unroll
        for (int g = 0; g < 5; ++g) w0[g] = *(const short8v*)(wt + wo[g]);
        #pragma unroll
        for (int g = 0; g < 5; ++g) w1[g] = *(const short8v*)(wt + (size_t)1 * (OO * 32) + wo[g]);
        #pragma unroll
        for (int g = 0; g < 5; ++g) w2[g] = *(const short8v*)(wt + (size_t)2 * (OO * 32) + wo[g]);
        #pragma unroll
        for (int g = 0; g < 5; ++g) w3[g] = *(const short8v*)(wt + (size_t)3 * (OO * 32) + wo[g]);

        #pragma unroll
        for (int kk = 0; kk < 10; ++kk) {
            const int r5 = kk % 5;
            short8v (&wcur)[5] = (r5 == 0) ? w0 : (r5 == 1) ? w1 : (r5 == 2) ? w2 : (r5 == 3) ? w3 : w4;
            short8v (&wnxt)[5] = (r5 == 0) ? w4 : (r5 == 1) ? w0 : (r5 == 2) ? w1 : (r5 == 3) ? w2 : w3;  // (kk+4)%5
            if (kk < 6) {
                const u16* wtn = wt + (size_t)(kk + 4) * (OO * 32);
                #pragma unroll
                for (int g = 0; g < 5; ++g)
                    wnxt[g] = *(const short8v*)(wtn + wo[g]);
            }
            int a_off = rowbase + ((kk * 64 + hi * 16) ^ swzl);
            short8v a0 = *(const short8v*)(sXb + a_off);
            short8v a1 = *(const short8v*)(sXb + a_off + 10240);
            short8v a2 = *(const short8v*)(sXb + a_off + 20480);
            short8v a3 = *(const short8v*)(sXb + a_off + 30720);
            #pragma unroll
            for (int g = 0; g < 5; ++g) {
                acc[g][0] = __builtin_amdgcn_mfma_f32_16x16x32_bf16(a0, wcur[g], acc[g][0], 0, 0, 0);
                acc[g][1] = __builtin_amdgcn_mfma_f32_16x16x32_bf16(a1, wcur[g], acc[g][1], 0, 0, 0);
                acc[g][2] = __builtin_amdgcn_mfma_f32_16x16x32_bf16(a2, wcur[g], acc[g][2], 0, 0, 0);
                acc[g][3] = __builtin_amdgcn_mfma_f32_16x16x32_bf16(a3, wcur[g], acc[g][3], 0, 0, 0);
            }
        }
    }

    // ---- phase 3: issue t1 gather FIRST (oldest), then bias, then c(t0) ----
    if (has1) {
        loadmeta(t1);
        if (q == 0) sMeta[1][r] = make_int4(sn, sl, sr2, 0);
        issue_stage();
    }
    __builtin_amdgcn_sched_barrier(0);   // pin: gather issued before c-loads

    float bb[5];
    #pragma unroll
    for (int g = 0; g < 5; ++g) bb[g] = bias[k0 * OO + g * 128 + hcol];

    int nodes[16];
    float cpl[16], cpr[16];
    #pragma unroll
    for (int m = 0; m < 4; ++m)
        #pragma unroll
        for (int jj = 0; jj < 4; ++jj) {
            int4 mt = sMeta[0][m * 16 + hi * 4 + jj];
            nodes[m * 4 + jj] = mt.x;
            cpl[m * 4 + jj] = c_pool[(size_t)mt.y * HV + hcol];
            cpr[m * 4 + jj] = c_pool[(size_t)mt.z * HV + hcol];
        }

    // ---- phase 4: epilogue t0 (c-wait drains the t1 gather for free) ----
    #pragma unroll
    for (int m = 0; m < 4; ++m) {
        #pragma unroll
        for (int jj = 0; jj < 4; ++jj) {
            int node = nodes[m * 4 + jj];
            if (node < 0) continue;
            float cl = cpl[m * 4 + jj], cr = cpr[m * 4 + jj];
            float gi  = acc[0][m][jj] + bb[0];
            float gfl = acc[1][m][jj] + bb[1];
            float gfr = acc[2][m][jj] + bb[2];
            float gu  = acc[3][m][jj] + bb[3];
            float go  = acc[4][m][jj] + bb[4];
            float cc = sigf(gi) * tanhfast(gu) + sigf(gfl) * cl + sigf(gfr) * cr;
            float hh = sigf(go) * tanhfast(cc);
            float* orow = out + (size_t)node * (2 * HV);
            orow[hcol]      = hh;
            orow[HV + hcol] = cc;
        }
    }

    if (!has1) return;

    // ---- phase 5: swap LDS to tile t1 (lgkm-only barriers) ----
    __builtin_amdgcn_s_barrier();                         // all waves done reading sX[t0]
    write_stage();
    asm volatile("s_waitcnt lgkmcnt(0)" ::: "memory");    // t1 LDS visible
    __builtin_amdgcn_s_barrier();

    // ---- tile t1: clean MFMA loop, 4-deep W prefetch ----
    int k1 = 0;
    #pragma unroll
    for (int j = 0; j < 7; ++j) k1 += (t1 >= hdr[17 + j]);

    #pragma unroll
    for (int g = 0; g < 5; ++g)
        #pragma unroll
        for (int m = 0; m < 4; ++m)
            acc[g][m] = (f32x4){0.f, 0.f, 0.f, 0.f};

    {
        const u16* __restrict__ wt = Wt + ((size_t)k1 * 10 * OO) * 32;
        short8v w0[5], w1[5], w2[5], w3[5], w4[5];
        #pragma unroll
        for (int g = 0; g < 5; ++g) w0[g] = *(const short8v*)(wt + wo[g]);
        #pragma unroll
        for (int g = 0; g < 5; ++g) w1[g] = *(const short8v*)(wt + (size_t)1 * (OO * 32) + wo[g]);
        #pragma unroll
        for (int g = 0; g < 5; ++g) w2[g] = *(const short8v*)(wt + (size_t)2 * (OO * 32) + wo[g]);
        #pragma unroll
        for (int g = 0; g < 5; ++g) w3[g] = *(const short8v*)(wt + (size_t)3 * (OO * 32) + wo[g]);

        #pragma unroll
        for (int kk = 0; kk < 10; ++kk) {
            const int r5 = kk % 5;
            short8v (&wcur)[5] = (r5 == 0) ? w0 : (r5 == 1) ? w1 : (r5 == 2) ? w2 : (r5 == 3) ? w3 : w4;
            short8v (&wnxt)[5] = (r5 == 0) ? w4 : (r5 == 1) ? w0 : (r5 == 2) ? w1 : (r5 == 3) ? w2 : w3;
            if (kk < 6) {
                const u16* wtn = wt + (size_t)(kk + 4) * (OO * 32);
                #pragma unroll
                for (int g = 0; g < 5; ++g)
                    wnxt[g] = *(const short8v*)(wtn + wo[g]);
            }
            int a_off = rowbase + ((kk * 64 + hi * 16) ^ swzl);
            short8v a0 = *(const short8v*)(sXb + a_off);
            short8v a1 = *(const short8v*)(sXb + a_off + 10240);
            short8v a2 = *(const short8v*)(sXb + a_off + 20480);
            short8v a3 = *(const short8v*)(sXb + a_off + 30720);
            #pragma unroll
            for (int g = 0; g < 5; ++g) {
                acc[g][0] = __builtin_amdgcn_mfma_f32_16x16x32_bf16(a0, wcur[g], acc[g][0], 0, 0, 0);
                acc[g][1] = __builtin_amdgcn_mfma_f32_16x16x32_bf16(a1, wcur[g], acc[g][1], 0, 0, 0);
                acc[g][2] = __builtin_amdgcn_mfma_f32_16x16x32_bf16(a2, wcur[g], acc[g][2], 0, 0, 0);
                acc[g][3] = __builtin_amdgcn_mfma_f32_16x16x32_bf16(a3, wcur[g], acc[g][3], 0, 0, 0);
            }
        }
    }

    // ---- t1 epilogue: bias + c after the loop ----
    #pragma unroll
    for (int g = 0; g < 5; ++g) bb[g] = bias[k1 * OO + g * 128 + hcol];

    #pragma unroll
    for (int m = 0; m < 4; ++m)
        #pragma unroll
        for (int jj = 0; jj < 4; ++jj) {
            int4 mt = sMeta[1][m * 16 + hi * 4 + jj];
            nodes[m * 4 + jj] = mt.x;
            cpl[m * 4 + jj] = c_pool[(size_t)mt.y * HV + hcol];
            cpr[m * 4 + jj] = c_pool[(size_t)mt.z * HV + hcol];
        }

    #pragma unroll
    for (int m = 0; m < 4; ++m) {
        #pragma unroll
        for (int jj = 0; jj < 4; ++jj) {
            int node = nodes[m * 4 + jj];
            if (node < 0) continue;
            float cl = cpl[m * 4 + jj], cr = cpr[m * 4 + jj];
            float gi  = acc[0][m][jj] + bb[0];
            float gfl = acc[1][m][jj] + bb[1];
            float gfr = acc[2][m][jj] + bb[2];
            float gu  = acc[3][m][jj] + bb[3];
            float go  = acc[4][m][jj] + bb[4];
            float cc = sigf(gi) * tanhfast(gu) + sigf(gfl) * cl + sigf(gfr) * cr;
            float hh = sigf(go) * tanhfast(cc);
            float* orow = out + (size_t)node * (2 * HV);
            orow[hcol]      = hh;
            orow[HV + hcol] = cc;
        }
    }
}

extern "C" void kernel_launch(void* const* d_in, const int* in_sizes, int n_in,
                              void* d_out, int out_size, void* d_ws, size_t ws_size,
                              hipStream_t stream) {
    const float* h_pool      = (const float*)d_in[0];
    const float* c_pool      = (const float*)d_in[1];
    const float* t_pool      = (const float*)d_in[2];
    const int*   child_idx   = (const int*)d_in[3];
    const int*   parent_type = (const int*)d_in[4];
    const float* W           = (const float*)d_in[5];
    const float* bias        = (const float*)d_in[6];
    float* out = (float*)d_out;

    const int N = in_sizes[3] / 2;
    const int maxblk = (N + RT - 1) / RT + KN;    // upper bound on row-tiles
    const int totrows = maxblk * RT;

    char* ws = (char*)d_ws;
    size_t off = 0;
    int* hdr = (int*)ws;                         off += 1024;
    int* idxbuf = (int*)(ws + off);              off += (((size_t)totrows * 4 + 255) / 256) * 256;
    u16* Wt = (u16*)(ws + off);                  off += (size_t)KN * OO * KP * 2;

    hipMemsetAsync(hdr, 0, 1024, stream);
    hipMemsetAsync(idxbuf, 0xFF, (size_t)totrows * 4, stream);

    int nb = (N + 255) / 256;
    hist_k<<<nb, 256, 0, stream>>>(parent_type, hdr, N);
    prefix_k<<<1, 64, 0, stream>>>(hdr);
    scatter_k<<<nb, 256, 0, stream>>>(parent_type, hdr, idxbuf, N);
    wconv_k<<<dim3((OO * KP + 255) / 256, KN), 256, 0, stream>>>(W, Wt);
    fused_k<<<(maxblk + 1) / 2, 512, 0, stream>>>(
        h_pool, c_pool, t_pool, child_idx, bias, Wt, hdr, idxbuf, out);
}